// Round 8
// baseline (87.200 us; speedup 1.0000x reference)
//
#include <hip/hip_runtime.h>

#define B_ 4
#define T_ 4096
#define E_ 1024
#define H_ 64

typedef __attribute__((ext_vector_type(8))) short short8;   // 8 x bf16 (4 VGPRs)
typedef __attribute__((ext_vector_type(4))) float f32x4;    // MFMA accumulator

static __device__ __forceinline__ unsigned short f2bf(float f) {
    unsigned int u = __builtin_bit_cast(unsigned int, f);
    u += 0x7fffu + ((u >> 16) & 1u);   // round-to-nearest-even
    return (unsigned short)(u >> 16);
}
static __device__ __forceinline__ float bf2f(unsigned short h) {
    unsigned int u = ((unsigned int)h) << 16;
    return __builtin_bit_cast(float, u);
}
#if __has_builtin(__builtin_amdgcn_exp2f)
#define EXP2(x) __builtin_amdgcn_exp2f(x)
#else
#define EXP2(x) exp2f(x)
#endif

#define GLOBAL_AS __attribute__((address_space(1)))
#define LDS_AS    __attribute__((address_space(3)))

// ---------------------------------------------------------------------------
// Kernel 1: transpose W [1024][64] f32 -> Wt [3][64][1024] bf16
// ---------------------------------------------------------------------------
__global__ __launch_bounds__(256) void wt_transpose_kernel(
    const float* __restrict__ Wq, const float* __restrict__ Wk,
    const float* __restrict__ Wv, unsigned short* __restrict__ Wt)
{
    __shared__ float tile[64][65];
    const int mat = blockIdx.x >> 4;
    const int kt  = blockIdx.x & 15;
    const float* W = (mat == 0) ? Wq : ((mat == 1) ? Wk : Wv);
    const int tid = threadIdx.x;
    #pragma unroll
    for (int p = 0; p < 16; ++p) {
        int idx = p * 256 + tid;
        tile[idx >> 6][idx & 63] = W[(kt * 64 + (idx >> 6)) * 64 + (idx & 63)];
    }
    __syncthreads();
    #pragma unroll
    for (int p = 0; p < 16; ++p) {
        int idx = p * 256 + tid;
        int h = idx >> 6, kl = idx & 63;
        Wt[(mat * 64 + h) * E_ + kt * 64 + kl] = f2bf(tile[kl][h]);
    }
}

// ---------------------------------------------------------------------------
// Kernel 2: fused QKV projection, round 8: 2 BLOCKS PER CU.
// proj was ~36us invariant across r5-r7 structures. The invariant: 1 block/CU
// (107 KB LDS). Each K-step's __syncthreads emits s_waitcnt vmcnt(0) -> the
// whole CU stalls on the staged HBM loads with NO sibling block to run
// (m114 overlap mechanism absent). Now: 32 rows/block, grid 512, 6 waves
// (3 mats x 2 row-groups, 384 thr), LDS = 16 KB (x dbuf) + 48 KB (Wt dbuf)
// = 64 KB -> 2 blocks/CU; the sibling block computes during this block's
// barrier drain. Staging/swizzle/epilogue per proven r5/r6 recipe.
// Q pre-scaled by (1/sqrt(E))*log2(e) for the attention exp2.
// ---------------------------------------------------------------------------
__global__ __launch_bounds__(384, 3) void proj_kernel(
    const float* __restrict__ x, const unsigned short* __restrict__ Wt,
    unsigned short* __restrict__ Qb, unsigned short* __restrict__ Kb,
    unsigned short* __restrict__ Vt)
{
    __shared__ float          x_lds[2][2048];    // 32 rows x 64 f32 (swizzled chunks)
    __shared__ unsigned short wt_lds[2][12288];  // 192 rows x 64 bf16 (swizzled chunks)
    const int tid  = threadIdx.x;
    const int wid  = tid >> 6, lane = tid & 63;
    const int g    = lane >> 4, c = lane & 15;
    const int mat  = wid >> 1;                   // 0=Q 1=K 2=V
    const int rg   = wid & 1;                    // 16-row group within block
    const int r0   = blockIdx.x * 32;
    const float QSCALE = 0.03125f * 1.44269504088896f;   // 1/sqrt(1024)*log2(e)

    // stage x[32 rows][kk..+64] (512 16B chunks) and Wt[192 rows][kk..+64]
    // (1536 chunks) into buffer buf. global src chunk = chunk ^ (row & mask)
    // (involution); LDS dest linear in chunk idx (wave-uniform base+lane*16).
    auto stage = [&](int buf, int kk) {
        {   // x: 512 chunks (16 f32-chunks per row), 384 + 128 threads
            int row = tid >> 4, ch = tid & 15;
            int csw = ch ^ (row & 15);
            const float* src = x + (size_t)(r0 + row) * E_ + kk + csw * 4;
            __builtin_amdgcn_global_load_lds(
                (const GLOBAL_AS unsigned int*)src,
                (LDS_AS unsigned int*)&x_lds[buf][(tid & ~63) * 4], 16, 0, 0);
            if (tid < 128) {
                int idx2 = 384 + tid;
                int row2 = idx2 >> 4, ch2 = idx2 & 15;
                int csw2 = ch2 ^ (row2 & 15);
                const float* src2 = x + (size_t)(r0 + row2) * E_ + kk + csw2 * 4;
                __builtin_amdgcn_global_load_lds(
                    (const GLOBAL_AS unsigned int*)src2,
                    (LDS_AS unsigned int*)&x_lds[buf][(idx2 & ~63) * 4], 16, 0, 0);
            }
        }
        #pragma unroll
        for (int p = 0; p < 4; ++p) {            // Wt: 1536 chunks (8 per row)
            int idx = p * 384 + tid;
            int row = idx >> 3, ch = idx & 7;
            int csw = ch ^ (row & 7);
            const unsigned short* src = Wt + (size_t)row * E_ + kk + csw * 8;
            __builtin_amdgcn_global_load_lds(
                (const GLOBAL_AS unsigned int*)src,
                (LDS_AS unsigned int*)&wt_lds[buf][(idx & ~63) * 8], 16, 0, 0);
        }
    };

    f32x4 acc[4];
    #pragma unroll
    for (int n = 0; n < 4; ++n) acc[n] = 0.0f;

    stage(0, 0);
    __syncthreads();

    for (int t = 0; t < 16; ++t) {
        const int buf = t & 1;
        if (t < 15) stage(buf ^ 1, (t + 1) * 64);

        const int xrowbase = (rg * 16 + c) * 64;
        const int wrowbase = (mat * 64 + c) * 64;
        #pragma unroll
        for (int kc = 0; kc < 2; ++kc) {
            // A frag: x row rg*16+c, k chunks (8kc+2g)^c, (8kc+2g+1)^c
            f32x4 xa = *(const f32x4*)&x_lds[buf][xrowbase + ((8 * kc + 2 * g)     ^ c) * 4];
            f32x4 xb = *(const f32x4*)&x_lds[buf][xrowbase + ((8 * kc + 2 * g + 1) ^ c) * 4];
            short8 a;
            #pragma unroll
            for (int j = 0; j < 4; ++j) {
                a[j]     = (short)f2bf(xa[j]);
                a[j + 4] = (short)f2bf(xb[j]);
            }
            // B frags: Wt row mat*64+n*16+c, k chunk (4kc+g)^(c&7)
            #pragma unroll
            for (int n = 0; n < 4; ++n) {
                short8 b = *(const short8*)
                    &wt_lds[buf][wrowbase + n * 1024 + (((4 * kc + g) ^ (c & 7)) * 8)];
                acc[n] = __builtin_amdgcn_mfma_f32_16x16x32_bf16(a, b, acc[n], 0, 0, 0);
            }
        }
        __syncthreads();
    }

    const int bb = r0 >> 12;                     // batch (blocks don't straddle)
    #pragma unroll
    for (int n = 0; n < 4; ++n)
        #pragma unroll
        for (int r = 0; r < 4; ++r) {
            int row = r0 + rg * 16 + 4 * g + r;
            int col = n * 16 + c;
            float v = acc[n][r];
            if (mat == 0)
                Qb[(size_t)row * H_ + col] = f2bf(v * QSCALE);
            else if (mat == 1)
                Kb[(size_t)row * H_ + col] = f2bf(v);
            else
                Vt[((size_t)bb * H_ + col) * T_ + (row & (T_ - 1))] = f2bf(v);
        }
}

// ---------------------------------------------------------------------------
// Kernel 3: split-K flash attention (round-5 version, unchanged).
// ---------------------------------------------------------------------------
__global__ __launch_bounds__(256, 3) void attn_split_kernel(
    const unsigned short* __restrict__ Qb, const unsigned short* __restrict__ Kb,
    const unsigned short* __restrict__ Vt, unsigned short* __restrict__ Po,
    float* __restrict__ Pl)
{
    __shared__ unsigned short K_lds[2][64][64];   // 16 KB (two 8 KB buffers)
    __shared__ unsigned short V_lds[2][64][64];   // 16 KB
    __shared__ unsigned short p_lds[4][16][72];   // 9 KB, per-wave P round-trip
    const int tid   = threadIdx.x;
    const int wid   = tid >> 6, lane = tid & 63;
    const int g     = lane >> 4, c = lane & 15;

    const int s     = blockIdx.x * 4 + wid;      // [0, 8192)
    const int batch = s >> 11;
    const int rem   = s & 2047;
    const int ch    = rem >> 8;                  // kv-chunk [0,8)
    const int qt    = rem & 255;                 // q-tile   [0,256)
    const int nkv   = (qt >> 2) + 1;             // total kv tiles for this qt
    if (ch * 8 >= nkv) return;                   // whole block exits together
    const int nt    = min(8, nkv - ch * 8);      // tiles in this chunk (same all waves)
    const int qbase = qt * 16;
    const int lastt = nkv - 1 - ch * 8;          // local idx of diagonal tile

    const int Mm = nkv - 1, aa = Mm >> 3, rr8 = Mm & 7;
    const int npart = (nkv + 7) >> 3;
    const int slot  = batch * 1152 + 4 * (4 * aa * (aa + 1) + rr8 * (aa + 1))
                    + (qt & 3) * npart + ch;

    const int rsub = lane >> 3;                  // staging: row-in-8
    const int csw  = (lane & 7) ^ rsub;          // involution chunk swizzle
    const int cs0 = (g ^ (c & 7)) * 8;           // read chunk offsets (lane-const)
    const int cs1 = ((g + 4) ^ (c & 7)) * 8;

    short8 aq0, aq1;                             // Q fragments (pre-scaled)
    {
        const unsigned short* qp = Qb + ((size_t)(batch * T_ + qbase + c)) * H_ + 8 * g;
        aq0 = *(const short8*)&qp[0];
        aq1 = *(const short8*)&qp[32];
    }

    short8 ones;                                 // bf16 1.0 fragment for l-MFMA
    #pragma unroll
    for (int j = 0; j < 8; ++j) ones[j] = (short)0x3F80;

    f32x4 o_acc[4];
    #pragma unroll
    for (int n = 0; n < 4; ++n) o_acc[n] = 0.0f;
    f32x4 l_acc = 0.0f;

    auto stage = [&](int buf, int gt) {
        const int key0 = gt * 64;
        #pragma unroll
        for (int j = 0; j < 2; ++j) {
            const int row = wid * 16 + j * 8;
            const unsigned short* gk = Kb
                + ((size_t)(batch * T_ + key0 + row + rsub)) * H_ + csw * 8;
            __builtin_amdgcn_global_load_lds(
                (const GLOBAL_AS unsigned int*)gk,
                (LDS_AS unsigned int*)&K_lds[buf][row][0], 16, 0, 0);
            const unsigned short* gv = Vt
                + ((size_t)(batch * H_ + row + rsub)) * T_ + key0 + csw * 8;
            __builtin_amdgcn_global_load_lds(
                (const GLOBAL_AS unsigned int*)gv,
                (LDS_AS unsigned int*)&V_lds[buf][row][0], 16, 0, 0);
        }
    };

    stage(0, ch * 8);
    __syncthreads();

    for (int t = 0; t < nt; ++t) {
        const int buf = t & 1;
        if (t + 1 < nt) stage(buf ^ 1, ch * 8 + t + 1);

        // ---- S = Q K^T (K frags from LDS, swizzled chunks) ----
        f32x4 sA[4];
        #pragma unroll
        for (int n = 0; n < 4; ++n) sA[n] = 0.0f;
        #pragma unroll
        for (int n = 0; n < 4; ++n) {
            short8 bk0 = *(const short8*)&K_lds[buf][n * 16 + c][cs0];
            short8 bk1 = *(const short8*)&K_lds[buf][n * 16 + c][cs1];
            sA[n] = __builtin_amdgcn_mfma_f32_16x16x32_bf16(aq0, bk0, sA[n], 0, 0, 0);
            sA[n] = __builtin_amdgcn_mfma_f32_16x16x32_bf16(aq1, bk1, sA[n], 0, 0, 0);
        }

        // ---- p = exp2(s); mask only the diagonal tile ----
        float pv[4][4];
        #pragma unroll
        for (int n = 0; n < 4; ++n)
            #pragma unroll
            for (int r = 0; r < 4; ++r)
                pv[n][r] = EXP2(sA[n][r]);
        if (t == lastt) {                        // wave-uniform branch
            const int d = (ch * 8 + t) * 64 + c - qbase - 4 * g;
            #pragma unroll
            for (int n = 0; n < 4; ++n)
                #pragma unroll
                for (int r = 0; r < 4; ++r)
                    if (d + 16 * n > r) pv[n][r] = 0.0f;
        }

        // ---- P: D-layout -> A-frag layout via per-wave LDS ----
        #pragma unroll
        for (int n = 0; n < 4; ++n)
            #pragma unroll
            for (int r = 0; r < 4; ++r)
                p_lds[wid][4 * g + r][n * 16 + c] = f2bf(pv[n][r]);
        short8 pa0 = *(const short8*)&p_lds[wid][c][8 * g];
        short8 pa1 = *(const short8*)&p_lds[wid][c][32 + 8 * g];

        // ---- l += P * 1 ----
        l_acc = __builtin_amdgcn_mfma_f32_16x16x32_bf16(pa0, ones, l_acc, 0, 0, 0);
        l_acc = __builtin_amdgcn_mfma_f32_16x16x32_bf16(pa1, ones, l_acc, 0, 0, 0);

        // ---- O += P V (V frags from LDS, swizzled chunks) ----
        #pragma unroll
        for (int n = 0; n < 4; ++n) {
            short8 bv0 = *(const short8*)&V_lds[buf][n * 16 + c][cs0];
            short8 bv1 = *(const short8*)&V_lds[buf][n * 16 + c][cs1];
            o_acc[n] = __builtin_amdgcn_mfma_f32_16x16x32_bf16(pa0, bv0, o_acc[n], 0, 0, 0);
            o_acc[n] = __builtin_amdgcn_mfma_f32_16x16x32_bf16(pa1, bv1, o_acc[n], 0, 0, 0);
        }

        __syncthreads();
    }

    unsigned short* po = Po + (size_t)slot * 1024;
    #pragma unroll
    for (int n = 0; n < 4; ++n)
        #pragma unroll
        for (int r = 0; r < 4; ++r)
            po[(4 * g + r) * 64 + n * 16 + c] = f2bf(o_acc[n][r]);
    if (c == 0) {
        #pragma unroll
        for (int r = 0; r < 4; ++r)
            Pl[slot * 16 + 4 * g + r] = l_acc[r];
    }
}

// ---------------------------------------------------------------------------
// Kernel 4: merge partials — plain sums. One wave per q-tile.
// ---------------------------------------------------------------------------
__global__ __launch_bounds__(256) void attn_merge_kernel(
    const unsigned short* __restrict__ Po, const float* __restrict__ Pl,
    float* __restrict__ out)
{
    const int tid  = threadIdx.x;
    const int wid  = tid >> 6, lane = tid & 63;
    const int gi   = blockIdx.x * 4 + wid;       // [0, 1024)
    const int batch = gi >> 8, qt = gi & 255;
    const int nkv  = (qt >> 2) + 1;
    const int npart = (nkv + 7) >> 3;
    const int Mm = nkv - 1, aa = Mm >> 3, rr8 = Mm & 7;
    const int slot0 = batch * 1152 + 4 * (4 * aa * (aa + 1) + rr8 * (aa + 1))
                    + (qt & 3) * npart;

    const int row = lane & 15, seg = lane >> 4;

    float lacc = 0.0f, o[16];
    #pragma unroll
    for (int k = 0; k < 16; ++k) o[k] = 0.0f;

    for (int i = 0; i < npart; ++i) {
        lacc += Pl[(slot0 + i) * 16 + row];
        const unsigned short* pp = Po + (size_t)(slot0 + i) * 1024 + row * 64 + seg * 16;
        short8 v0 = *(const short8*)&pp[0];
        short8 v1 = *(const short8*)&pp[8];
        #pragma unroll
        for (int k = 0; k < 8; ++k) {
            o[k]     += bf2f((unsigned short)v0[k]);
            o[8 + k] += bf2f((unsigned short)v1[k]);
        }
    }

    const float inv = 1.0f / lacc;
    float* op = out + ((size_t)(batch * T_ + qt * 16 + row)) * H_ + seg * 16;
    #pragma unroll
    for (int k = 0; k < 16; ++k) op[k] = o[k] * inv;
}

// ---------------------------------------------------------------------------
extern "C" void kernel_launch(void* const* d_in, const int* in_sizes, int n_in,
                              void* d_out, int out_size, void* d_ws, size_t ws_size,
                              hipStream_t stream)
{
    const float* x  = (const float*)d_in[0];
    const float* Wk = (const float*)d_in[1];
    const float* Wq = (const float*)d_in[2];
    const float* Wv = (const float*)d_in[3];
    float* out = (float*)d_out;

    // workspace layout:
    //   Wt  [3*64*1024] bf16            384 KB
    //   Qb/Kb [B*T*H] bf16            2+2 MB
    //   Vt  [B*H*T] bf16                  2 MB
    //   Po  [4608][16][64] bf16         9.4 MB
    //   Pl  [4608][16] f32              295 KB   total ~16.1 MB
    unsigned short* Wt = (unsigned short*)d_ws;
    unsigned short* Qb = Wt + 3 * 64 * 1024;
    unsigned short* Kb = Qb + (size_t)B_ * T_ * H_;
    unsigned short* Vt = Kb + (size_t)B_ * T_ * H_;
    unsigned short* Po = Vt + (size_t)B_ * T_ * H_;
    float* Pl = (float*)(Po + (size_t)4608 * 1024);

    hipLaunchKernelGGL(wt_transpose_kernel, dim3(48), dim3(256), 0, stream, Wq, Wk, Wv, Wt);
    hipLaunchKernelGGL(proj_kernel, dim3(512), dim3(384), 0, stream, x, Wt, Qb, Kb, Vt);
    hipLaunchKernelGGL(attn_split_kernel, dim3(2048), dim3(256), 0, stream, Qb, Kb, Vt, Po, Pl);
    hipLaunchKernelGGL(attn_merge_kernel, dim3(256), dim3(256), 0, stream, Po, Pl, out);
}

// Round 9
// 74.112 us; speedup vs baseline: 1.1766x; 1.1766x over previous
//
#include <hip/hip_runtime.h>

#define B_ 4
#define T_ 4096
#define E_ 1024
#define H_ 64

typedef __attribute__((ext_vector_type(8))) short short8;   // 8 x bf16 (4 VGPRs)
typedef __attribute__((ext_vector_type(4))) float f32x4;    // MFMA accumulator

static __device__ __forceinline__ unsigned short f2bf(float f) {
    unsigned int u = __builtin_bit_cast(unsigned int, f);
    u += 0x7fffu + ((u >> 16) & 1u);   // round-to-nearest-even
    return (unsigned short)(u >> 16);
}
static __device__ __forceinline__ float bf2f(unsigned short h) {
    unsigned int u = ((unsigned int)h) << 16;
    return __builtin_bit_cast(float, u);
}
#if __has_builtin(__builtin_amdgcn_exp2f)
#define EXP2(x) __builtin_amdgcn_exp2f(x)
#else
#define EXP2(x) exp2f(x)
#endif

#define GLOBAL_AS __attribute__((address_space(1)))
#define LDS_AS    __attribute__((address_space(3)))

// ---------------------------------------------------------------------------
// Kernel 1: transpose W [1024][64] f32 -> Wt [3][64][1024] bf16
// ---------------------------------------------------------------------------
__global__ __launch_bounds__(256) void wt_transpose_kernel(
    const float* __restrict__ Wq, const float* __restrict__ Wk,
    const float* __restrict__ Wv, unsigned short* __restrict__ Wt)
{
    __shared__ float tile[64][65];
    const int mat = blockIdx.x >> 4;
    const int kt  = blockIdx.x & 15;
    const float* W = (mat == 0) ? Wq : ((mat == 1) ? Wk : Wv);
    const int tid = threadIdx.x;
    #pragma unroll
    for (int p = 0; p < 16; ++p) {
        int idx = p * 256 + tid;
        tile[idx >> 6][idx & 63] = W[(kt * 64 + (idx >> 6)) * 64 + (idx & 63)];
    }
    __syncthreads();
    #pragma unroll
    for (int p = 0; p < 16; ++p) {
        int idx = p * 256 + tid;
        int h = idx >> 6, kl = idx & 63;
        Wt[(mat * 64 + h) * E_ + kt * 64 + kl] = f2bf(tile[kl][h]);
    }
}

// ---------------------------------------------------------------------------
// Kernel 2: fused QKV projection, round 9.
// Model v3 (from r8 falsification): the wall is per-CU global_load_lds DMA
// volume (~41 KB/K-step at ~25 B/cy ingest), not occupancy. So:
//  - x is NO LONGER DMA-staged: each wave loads its 16 rows' fragments
//    direct to REGISTERS, software-prefetched ONE K-step ahead (named
//    xA/xB sets, explicit unroll-2 so all indices are static).
//  - only Wt is DMA-staged (24 KB/step, dbuf, proven involution swizzle).
//  - counted-vmcnt barrier: "s_waitcnt vmcnt(4); s_barrier" leaves the 4
//    x-prefetch loads in flight across the barrier; waves drain only their
//    own 2 Wt-stage ops (symmetric -> buffer globally ready after barrier).
// 768 thr (12 waves = 3 mats x 4 row-groups), grid 256, LDS 48 KB.
// Q pre-scaled by (1/sqrt(E))*log2(e) for the attention exp2.
// ---------------------------------------------------------------------------
__global__ __launch_bounds__(768, 1) void proj_kernel(
    const float* __restrict__ x, const unsigned short* __restrict__ Wt,
    unsigned short* __restrict__ Qb, unsigned short* __restrict__ Kb,
    unsigned short* __restrict__ Vt)
{
    __shared__ unsigned short wt_lds[2][12288];  // 192 rows x 64 bf16, dbuf, swizzled
    const int tid  = threadIdx.x;
    const int wid  = tid >> 6, lane = tid & 63;
    const int g    = lane >> 4, c = lane & 15;
    const int mat  = wid >> 2;                   // 0=Q 1=K 2=V
    const int rg   = wid & 3;                    // 16-row group within block
    const int r0   = blockIdx.x * 64;
    const float QSCALE = 0.03125f * 1.44269504088896f;   // 1/sqrt(1024)*log2(e)

    const float* xrow = x + (size_t)(r0 + rg * 16 + c) * E_;   // this lane's A-row

    // Wt stage: 1536 16B-chunks over 768 threads (2 instrs each).
    auto stageWt = [&](int buf, int kk) {
        #pragma unroll
        for (int p = 0; p < 2; ++p) {
            int idx = p * 768 + tid;
            int row = idx >> 3, ch = idx & 7;
            int csw = ch ^ (row & 7);            // involution chunk swizzle
            const unsigned short* src = Wt + (size_t)row * E_ + kk + csw * 8;
            __builtin_amdgcn_global_load_lds(
                (const GLOBAL_AS unsigned int*)src,
                (LDS_AS unsigned int*)&wt_lds[buf][(idx & ~63) * 8], 16, 0, 0);
        }
    };
    // x prefetch: 4 x 16B register loads for one K-step.
    auto loadx = [&](f32x4* dst, int t) {
        const float* xr = xrow + t * 64;
        dst[0] = *(const f32x4*)&xr[8 * g];
        dst[1] = *(const f32x4*)&xr[8 * g + 4];
        dst[2] = *(const f32x4*)&xr[32 + 8 * g];
        dst[3] = *(const f32x4*)&xr[32 + 8 * g + 4];
    };

    f32x4 acc[4];
    #pragma unroll
    for (int n = 0; n < 4; ++n) acc[n] = 0.0f;

    const int wrowbase = (mat * 64 + c) * 64;
    auto computeStep = [&](int buf, const f32x4* xs) {
        #pragma unroll
        for (int kc = 0; kc < 2; ++kc) {
            short8 a;
            #pragma unroll
            for (int j = 0; j < 4; ++j) {
                a[j]     = (short)f2bf(xs[kc * 2][j]);
                a[j + 4] = (short)f2bf(xs[kc * 2 + 1][j]);
            }
            #pragma unroll
            for (int n = 0; n < 4; ++n) {
                short8 b = *(const short8*)
                    &wt_lds[buf][wrowbase + n * 1024 + (((4 * kc + g) ^ (c & 7)) * 8)];
                acc[n] = __builtin_amdgcn_mfma_f32_16x16x32_bf16(a, b, acc[n], 0, 0, 0);
            }
        }
    };

    f32x4 xA[4], xB[4];
    stageWt(0, 0);
    asm volatile("" ::: "memory");               // order: stage before prefetch
    loadx(xA, 0);
    asm volatile("s_waitcnt vmcnt(0)\n\ts_barrier" ::: "memory");

    #pragma unroll
    for (int tt = 0; tt < 16; tt += 2) {
        // even step: compute buf0 with xA; stage/prefetch tt+1
        stageWt(1, (tt + 1) * 64);
        asm volatile("" ::: "memory");
        loadx(xB, tt + 1);
        computeStep(0, xA);
        asm volatile("s_waitcnt vmcnt(4)\n\ts_barrier" ::: "memory");

        // odd step: compute buf1 with xB; stage/prefetch tt+2 (if any)
        if (tt + 2 < 16) {
            stageWt(0, (tt + 2) * 64);
            asm volatile("" ::: "memory");
            loadx(xA, tt + 2);
            computeStep(1, xB);
            asm volatile("s_waitcnt vmcnt(4)\n\ts_barrier" ::: "memory");
        } else {
            computeStep(1, xB);                  // last step: no stage, no barrier
        }
    }

    const int bb = r0 >> 12;                     // batch (blocks don't straddle)
    #pragma unroll
    for (int n = 0; n < 4; ++n)
        #pragma unroll
        for (int r = 0; r < 4; ++r) {
            int row = r0 + rg * 16 + 4 * g + r;
            int col = n * 16 + c;
            float v = acc[n][r];
            if (mat == 0)
                Qb[(size_t)row * H_ + col] = f2bf(v * QSCALE);
            else if (mat == 1)
                Kb[(size_t)row * H_ + col] = f2bf(v);
            else
                Vt[((size_t)bb * H_ + col) * T_ + (row & (T_ - 1))] = f2bf(v);
        }
}

// ---------------------------------------------------------------------------
// Kernel 3: split-K flash attention (round-5 version, unchanged).
// ---------------------------------------------------------------------------
__global__ __launch_bounds__(256, 3) void attn_split_kernel(
    const unsigned short* __restrict__ Qb, const unsigned short* __restrict__ Kb,
    const unsigned short* __restrict__ Vt, unsigned short* __restrict__ Po,
    float* __restrict__ Pl)
{
    __shared__ unsigned short K_lds[2][64][64];   // 16 KB (two 8 KB buffers)
    __shared__ unsigned short V_lds[2][64][64];   // 16 KB
    __shared__ unsigned short p_lds[4][16][72];   // 9 KB, per-wave P round-trip
    const int tid   = threadIdx.x;
    const int wid   = tid >> 6, lane = tid & 63;
    const int g     = lane >> 4, c = lane & 15;

    const int s     = blockIdx.x * 4 + wid;      // [0, 8192)
    const int batch = s >> 11;
    const int rem   = s & 2047;
    const int ch    = rem >> 8;                  // kv-chunk [0,8)
    const int qt    = rem & 255;                 // q-tile   [0,256)
    const int nkv   = (qt >> 2) + 1;             // total kv tiles for this qt
    if (ch * 8 >= nkv) return;                   // whole block exits together
    const int nt    = min(8, nkv - ch * 8);      // tiles in this chunk (same all waves)
    const int qbase = qt * 16;
    const int lastt = nkv - 1 - ch * 8;          // local idx of diagonal tile

    const int Mm = nkv - 1, aa = Mm >> 3, rr8 = Mm & 7;
    const int npart = (nkv + 7) >> 3;
    const int slot  = batch * 1152 + 4 * (4 * aa * (aa + 1) + rr8 * (aa + 1))
                    + (qt & 3) * npart + ch;

    const int rsub = lane >> 3;                  // staging: row-in-8
    const int csw  = (lane & 7) ^ rsub;          // involution chunk swizzle
    const int cs0 = (g ^ (c & 7)) * 8;           // read chunk offsets (lane-const)
    const int cs1 = ((g + 4) ^ (c & 7)) * 8;

    short8 aq0, aq1;                             // Q fragments (pre-scaled)
    {
        const unsigned short* qp = Qb + ((size_t)(batch * T_ + qbase + c)) * H_ + 8 * g;
        aq0 = *(const short8*)&qp[0];
        aq1 = *(const short8*)&qp[32];
    }

    short8 ones;                                 // bf16 1.0 fragment for l-MFMA
    #pragma unroll
    for (int j = 0; j < 8; ++j) ones[j] = (short)0x3F80;

    f32x4 o_acc[4];
    #pragma unroll
    for (int n = 0; n < 4; ++n) o_acc[n] = 0.0f;
    f32x4 l_acc = 0.0f;

    auto stage = [&](int buf, int gt) {
        const int key0 = gt * 64;
        #pragma unroll
        for (int j = 0; j < 2; ++j) {
            const int row = wid * 16 + j * 8;
            const unsigned short* gk = Kb
                + ((size_t)(batch * T_ + key0 + row + rsub)) * H_ + csw * 8;
            __builtin_amdgcn_global_load_lds(
                (const GLOBAL_AS unsigned int*)gk,
                (LDS_AS unsigned int*)&K_lds[buf][row][0], 16, 0, 0);
            const unsigned short* gv = Vt
                + ((size_t)(batch * H_ + row + rsub)) * T_ + key0 + csw * 8;
            __builtin_amdgcn_global_load_lds(
                (const GLOBAL_AS unsigned int*)gv,
                (LDS_AS unsigned int*)&V_lds[buf][row][0], 16, 0, 0);
        }
    };

    stage(0, ch * 8);
    __syncthreads();

    for (int t = 0; t < nt; ++t) {
        const int buf = t & 1;
        if (t + 1 < nt) stage(buf ^ 1, ch * 8 + t + 1);

        // ---- S = Q K^T (K frags from LDS, swizzled chunks) ----
        f32x4 sA[4];
        #pragma unroll
        for (int n = 0; n < 4; ++n) sA[n] = 0.0f;
        #pragma unroll
        for (int n = 0; n < 4; ++n) {
            short8 bk0 = *(const short8*)&K_lds[buf][n * 16 + c][cs0];
            short8 bk1 = *(const short8*)&K_lds[buf][n * 16 + c][cs1];
            sA[n] = __builtin_amdgcn_mfma_f32_16x16x32_bf16(aq0, bk0, sA[n], 0, 0, 0);
            sA[n] = __builtin_amdgcn_mfma_f32_16x16x32_bf16(aq1, bk1, sA[n], 0, 0, 0);
        }

        // ---- p = exp2(s); mask only the diagonal tile ----
        float pv[4][4];
        #pragma unroll
        for (int n = 0; n < 4; ++n)
            #pragma unroll
            for (int r = 0; r < 4; ++r)
                pv[n][r] = EXP2(sA[n][r]);
        if (t == lastt) {                        // wave-uniform branch
            const int d = (ch * 8 + t) * 64 + c - qbase - 4 * g;
            #pragma unroll
            for (int n = 0; n < 4; ++n)
                #pragma unroll
                for (int r = 0; r < 4; ++r)
                    if (d + 16 * n > r) pv[n][r] = 0.0f;
        }

        // ---- P: D-layout -> A-frag layout via per-wave LDS ----
        #pragma unroll
        for (int n = 0; n < 4; ++n)
            #pragma unroll
            for (int r = 0; r < 4; ++r)
                p_lds[wid][4 * g + r][n * 16 + c] = f2bf(pv[n][r]);
        short8 pa0 = *(const short8*)&p_lds[wid][c][8 * g];
        short8 pa1 = *(const short8*)&p_lds[wid][c][32 + 8 * g];

        // ---- l += P * 1 ----
        l_acc = __builtin_amdgcn_mfma_f32_16x16x32_bf16(pa0, ones, l_acc, 0, 0, 0);
        l_acc = __builtin_amdgcn_mfma_f32_16x16x32_bf16(pa1, ones, l_acc, 0, 0, 0);

        // ---- O += P V (V frags from LDS, swizzled chunks) ----
        #pragma unroll
        for (int n = 0; n < 4; ++n) {
            short8 bv0 = *(const short8*)&V_lds[buf][n * 16 + c][cs0];
            short8 bv1 = *(const short8*)&V_lds[buf][n * 16 + c][cs1];
            o_acc[n] = __builtin_amdgcn_mfma_f32_16x16x32_bf16(pa0, bv0, o_acc[n], 0, 0, 0);
            o_acc[n] = __builtin_amdgcn_mfma_f32_16x16x32_bf16(pa1, bv1, o_acc[n], 0, 0, 0);
        }

        __syncthreads();
    }

    unsigned short* po = Po + (size_t)slot * 1024;
    #pragma unroll
    for (int n = 0; n < 4; ++n)
        #pragma unroll
        for (int r = 0; r < 4; ++r)
            po[(4 * g + r) * 64 + n * 16 + c] = f2bf(o_acc[n][r]);
    if (c == 0) {
        #pragma unroll
        for (int r = 0; r < 4; ++r)
            Pl[slot * 16 + 4 * g + r] = l_acc[r];
    }
}

// ---------------------------------------------------------------------------
// Kernel 4: merge partials — plain sums. One wave per q-tile.
// ---------------------------------------------------------------------------
__global__ __launch_bounds__(256) void attn_merge_kernel(
    const unsigned short* __restrict__ Po, const float* __restrict__ Pl,
    float* __restrict__ out)
{
    const int tid  = threadIdx.x;
    const int wid  = tid >> 6, lane = tid & 63;
    const int gi   = blockIdx.x * 4 + wid;       // [0, 1024)
    const int batch = gi >> 8, qt = gi & 255;
    const int nkv  = (qt >> 2) + 1;
    const int npart = (nkv + 7) >> 3;
    const int Mm = nkv - 1, aa = Mm >> 3, rr8 = Mm & 7;
    const int slot0 = batch * 1152 + 4 * (4 * aa * (aa + 1) + rr8 * (aa + 1))
                    + (qt & 3) * npart;

    const int row = lane & 15, seg = lane >> 4;

    float lacc = 0.0f, o[16];
    #pragma unroll
    for (int k = 0; k < 16; ++k) o[k] = 0.0f;

    for (int i = 0; i < npart; ++i) {
        lacc += Pl[(slot0 + i) * 16 + row];
        const unsigned short* pp = Po + (size_t)(slot0 + i) * 1024 + row * 64 + seg * 16;
        short8 v0 = *(const short8*)&pp[0];
        short8 v1 = *(const short8*)&pp[8];
        #pragma unroll
        for (int k = 0; k < 8; ++k) {
            o[k]     += bf2f((unsigned short)v0[k]);
            o[8 + k] += bf2f((unsigned short)v1[k]);
        }
    }

    const float inv = 1.0f / lacc;
    float* op = out + ((size_t)(batch * T_ + qt * 16 + row)) * H_ + seg * 16;
    #pragma unroll
    for (int k = 0; k < 16; ++k) op[k] = o[k] * inv;
}

// ---------------------------------------------------------------------------
extern "C" void kernel_launch(void* const* d_in, const int* in_sizes, int n_in,
                              void* d_out, int out_size, void* d_ws, size_t ws_size,
                              hipStream_t stream)
{
    const float* x  = (const float*)d_in[0];
    const float* Wk = (const float*)d_in[1];
    const float* Wq = (const float*)d_in[2];
    const float* Wv = (const float*)d_in[3];
    float* out = (float*)d_out;

    // workspace layout:
    //   Wt  [3*64*1024] bf16            384 KB
    //   Qb/Kb [B*T*H] bf16            2+2 MB
    //   Vt  [B*H*T] bf16                  2 MB
    //   Po  [4608][16][64] bf16         9.4 MB
    //   Pl  [4608][16] f32              295 KB   total ~16.1 MB
    unsigned short* Wt = (unsigned short*)d_ws;
    unsigned short* Qb = Wt + 3 * 64 * 1024;
    unsigned short* Kb = Qb + (size_t)B_ * T_ * H_;
    unsigned short* Vt = Kb + (size_t)B_ * T_ * H_;
    unsigned short* Po = Vt + (size_t)B_ * T_ * H_;
    float* Pl = (float*)(Po + (size_t)4608 * 1024);

    hipLaunchKernelGGL(wt_transpose_kernel, dim3(48), dim3(256), 0, stream, Wq, Wk, Wv, Wt);
    hipLaunchKernelGGL(proj_kernel, dim3(256), dim3(768), 0, stream, x, Wt, Qb, Kb, Vt);
    hipLaunchKernelGGL(attn_split_kernel, dim3(2048), dim3(256), 0, stream, Qb, Kb, Vt, Po, Pl);
    hipLaunchKernelGGL(attn_merge_kernel, dim3(256), dim3(256), 0, stream, Po, Pl, out);
}

// Round 10
// 59.703 us; speedup vs baseline: 1.4606x; 1.2414x over previous
//
#include <hip/hip_runtime.h>

#define B_ 4
#define T_ 4096
#define E_ 1024
#define H_ 64

typedef __attribute__((ext_vector_type(8))) short short8;   // 8 x bf16 (4 VGPRs)
typedef __attribute__((ext_vector_type(4))) float f32x4;    // MFMA accumulator

static __device__ __forceinline__ unsigned short f2bf(float f) {
    unsigned int u = __builtin_bit_cast(unsigned int, f);
    u += 0x7fffu + ((u >> 16) & 1u);   // round-to-nearest-even
    return (unsigned short)(u >> 16);
}
static __device__ __forceinline__ float bf2f(unsigned short h) {
    unsigned int u = ((unsigned int)h) << 16;
    return __builtin_bit_cast(float, u);
}
#if __has_builtin(__builtin_amdgcn_exp2f)
#define EXP2(x) __builtin_amdgcn_exp2f(x)
#else
#define EXP2(x) exp2f(x)
#endif

#define GLOBAL_AS __attribute__((address_space(1)))
#define LDS_AS    __attribute__((address_space(3)))

// ---------------------------------------------------------------------------
// Kernel 1: transpose W [1024][64] f32 -> Wt [3][64][1024] bf16
// ---------------------------------------------------------------------------
__global__ __launch_bounds__(256) void wt_transpose_kernel(
    const float* __restrict__ Wq, const float* __restrict__ Wk,
    const float* __restrict__ Wv, unsigned short* __restrict__ Wt)
{
    __shared__ float tile[64][65];
    const int mat = blockIdx.x >> 4;
    const int kt  = blockIdx.x & 15;
    const float* W = (mat == 0) ? Wq : ((mat == 1) ? Wk : Wv);
    const int tid = threadIdx.x;
    #pragma unroll
    for (int p = 0; p < 16; ++p) {
        int idx = p * 256 + tid;
        tile[idx >> 6][idx & 63] = W[(kt * 64 + (idx >> 6)) * 64 + (idx & 63)];
    }
    __syncthreads();
    #pragma unroll
    for (int p = 0; p < 16; ++p) {
        int idx = p * 256 + tid;
        int h = idx >> 6, kl = idx & 63;
        Wt[(mat * 64 + h) * E_ + kt * 64 + kl] = f2bf(tile[kl][h]);
    }
}

// ---------------------------------------------------------------------------
// Kernel 2: fused QKV projection, round 10.
// History: proj ~36-47us across r5-r9; falsified theories: occupancy (r8),
// DMA volume (r9), store scatter (r7). Model v4: ~4000cy/step of DMA
// completion latency exposed at each barrier (1 block/CU, nothing to
// overlap). Fix: DEPTH. r7's proven all-DMA staging, but with THREE LDS
// buffers (120 KB) and stage issued TWO steps ahead; counted-vmcnt barrier
// drains only stage(t+1) while stage(t+2) stays in flight -> each stage
// gets ~2 full steps (compute+barrier) of cover.
// Per-wave vmem counts per stage(): waves 0-3 issue 4 instrs (2 x-DMA +
// 2 Wt-DMA), waves 4-11 issue 3 (1+2) -> per-wave vmcnt constants via a
// wave-uniform branch. Compute issues NO vmem, so counts are exact.
// WAR safety: buffer reuse distance 3; every ds_read is consumed by an
// in-iteration MFMA (compiler lgkmcnt) before the wave reaches its barrier.
// Q pre-scaled by (1/sqrt(E))*log2(e) for the attention exp2.
// ---------------------------------------------------------------------------
__global__ __launch_bounds__(768, 1) void proj_kernel(
    const float* __restrict__ x, const unsigned short* __restrict__ Wt,
    unsigned short* __restrict__ Qb, unsigned short* __restrict__ Kb,
    unsigned short* __restrict__ Vt)
{
    __shared__ float          x_lds[3][4096];    // 64 rows x 64 f32, swizzled chunks
    __shared__ unsigned short wt_lds[3][12288];  // 192 rows x 64 bf16, swizzled chunks
    const int tid  = threadIdx.x;
    const int wid  = tid >> 6, lane = tid & 63;
    const int g    = lane >> 4, c = lane & 15;
    const int mat  = wid >> 2;                   // 0=Q 1=K 2=V
    const int rg   = wid & 3;                    // 16-row group within block
    const int r0   = blockIdx.x * 64;
    const float QSCALE = 0.03125f * 1.44269504088896f;   // 1/sqrt(1024)*log2(e)

    // stage x[64 rows][kk..+64] (1024 16B chunks) + Wt[192 rows][kk..+64]
    // (1536 chunks). Involution chunk swizzle on the GLOBAL side; LDS linear.
    auto stage = [&](int buf, int kk) {
        {   // x: chunk idx = row*16+ch; LDS float offset = idx*4
            int row = tid >> 4, ch = tid & 15;
            int csw = ch ^ (row & 15);
            const float* src = x + (size_t)(r0 + row) * E_ + kk + csw * 4;
            __builtin_amdgcn_global_load_lds(
                (const GLOBAL_AS unsigned int*)src,
                (LDS_AS unsigned int*)&x_lds[buf][(tid & ~63) * 4], 16, 0, 0);
            if (tid < 256) {                     // waves 0-3: chunks 768..1023
                int idx2 = 768 + tid;
                int row2 = idx2 >> 4, ch2 = idx2 & 15;
                int csw2 = ch2 ^ (row2 & 15);
                const float* src2 = x + (size_t)(r0 + row2) * E_ + kk + csw2 * 4;
                __builtin_amdgcn_global_load_lds(
                    (const GLOBAL_AS unsigned int*)src2,
                    (LDS_AS unsigned int*)&x_lds[buf][(idx2 & ~63) * 4], 16, 0, 0);
            }
        }
        #pragma unroll
        for (int p = 0; p < 2; ++p) {            // Wt: 1536 chunks (8 per row)
            int idx = p * 768 + tid;
            int row = idx >> 3, ch = idx & 7;
            int csw = ch ^ (row & 7);
            const unsigned short* src = Wt + (size_t)row * E_ + kk + csw * 8;
            __builtin_amdgcn_global_load_lds(
                (const GLOBAL_AS unsigned int*)src,
                (LDS_AS unsigned int*)&wt_lds[buf][(idx & ~63) * 8], 16, 0, 0);
        }
    };

    f32x4 acc[4];
    #pragma unroll
    for (int n = 0; n < 4; ++n) acc[n] = 0.0f;

    const int xrowbase = (rg * 16 + c) * 64;
    const int wrowbase = (mat * 64 + c) * 64;
    auto computeStep = [&](int buf) {
        #pragma unroll
        for (int kc = 0; kc < 2; ++kc) {
            f32x4 xa = *(const f32x4*)&x_lds[buf][xrowbase + ((8 * kc + 2 * g)     ^ c) * 4];
            f32x4 xb = *(const f32x4*)&x_lds[buf][xrowbase + ((8 * kc + 2 * g + 1) ^ c) * 4];
            short8 a;
            #pragma unroll
            for (int j = 0; j < 4; ++j) {
                a[j]     = (short)f2bf(xa[j]);
                a[j + 4] = (short)f2bf(xb[j]);
            }
            #pragma unroll
            for (int n = 0; n < 4; ++n) {
                short8 b = *(const short8*)
                    &wt_lds[buf][wrowbase + n * 1024 + (((4 * kc + g) ^ (c & 7)) * 8)];
                acc[n] = __builtin_amdgcn_mfma_f32_16x16x32_bf16(a, b, acc[n], 0, 0, 0);
            }
        }
    };

    // counted-vmcnt barrier: drain the oldest stage, leave one (4 or 3
    // instrs, per wave) in flight. Wave-uniform branch; single barrier after.
    auto waitKeepOne = [&]() {
        if (wid < 4) asm volatile("s_waitcnt vmcnt(4)" ::: "memory");
        else         asm volatile("s_waitcnt vmcnt(3)" ::: "memory");
        __builtin_amdgcn_s_barrier();
    };

    stage(0, 0);
    stage(1, 64);
    waitKeepOne();                               // drain stage0, stage1 in flight

    #pragma unroll
    for (int t = 0; t < 16; ++t) {
        if (t + 2 < 16) stage((t + 2) % 3, (t + 2) * 64);
        computeStep(t % 3);
        if (t + 2 < 16) {
            waitKeepOne();                       // drain stage(t+1), keep stage(t+2)
        } else if (t == 14) {
            asm volatile("s_waitcnt vmcnt(0)" ::: "memory");   // drain stage(15)
            __builtin_amdgcn_s_barrier();
        }                                        // t==15: fall through to epilogue
    }

    const int bb = r0 >> 12;                     // batch (blocks don't straddle)
    #pragma unroll
    for (int n = 0; n < 4; ++n)
        #pragma unroll
        for (int r = 0; r < 4; ++r) {
            int row = r0 + rg * 16 + 4 * g + r;
            int col = n * 16 + c;
            float v = acc[n][r];
            if (mat == 0)
                Qb[(size_t)row * H_ + col] = f2bf(v * QSCALE);
            else if (mat == 1)
                Kb[(size_t)row * H_ + col] = f2bf(v);
            else
                Vt[((size_t)bb * H_ + col) * T_ + (row & (T_ - 1))] = f2bf(v);
        }
}

// ---------------------------------------------------------------------------
// Kernel 3: split-K flash attention (round-5 version, unchanged).
// ---------------------------------------------------------------------------
__global__ __launch_bounds__(256, 3) void attn_split_kernel(
    const unsigned short* __restrict__ Qb, const unsigned short* __restrict__ Kb,
    const unsigned short* __restrict__ Vt, unsigned short* __restrict__ Po,
    float* __restrict__ Pl)
{
    __shared__ unsigned short K_lds[2][64][64];   // 16 KB (two 8 KB buffers)
    __shared__ unsigned short V_lds[2][64][64];   // 16 KB
    __shared__ unsigned short p_lds[4][16][72];   // 9 KB, per-wave P round-trip
    const int tid   = threadIdx.x;
    const int wid   = tid >> 6, lane = tid & 63;
    const int g     = lane >> 4, c = lane & 15;

    const int s     = blockIdx.x * 4 + wid;      // [0, 8192)
    const int batch = s >> 11;
    const int rem   = s & 2047;
    const int ch    = rem >> 8;                  // kv-chunk [0,8)
    const int qt    = rem & 255;                 // q-tile   [0,256)
    const int nkv   = (qt >> 2) + 1;             // total kv tiles for this qt
    if (ch * 8 >= nkv) return;                   // whole block exits together
    const int nt    = min(8, nkv - ch * 8);      // tiles in this chunk (same all waves)
    const int qbase = qt * 16;
    const int lastt = nkv - 1 - ch * 8;          // local idx of diagonal tile

    const int Mm = nkv - 1, aa = Mm >> 3, rr8 = Mm & 7;
    const int npart = (nkv + 7) >> 3;
    const int slot  = batch * 1152 + 4 * (4 * aa * (aa + 1) + rr8 * (aa + 1))
                    + (qt & 3) * npart + ch;

    const int rsub = lane >> 3;                  // staging: row-in-8
    const int csw  = (lane & 7) ^ rsub;          // involution chunk swizzle
    const int cs0 = (g ^ (c & 7)) * 8;           // read chunk offsets (lane-const)
    const int cs1 = ((g + 4) ^ (c & 7)) * 8;

    short8 aq0, aq1;                             // Q fragments (pre-scaled)
    {
        const unsigned short* qp = Qb + ((size_t)(batch * T_ + qbase + c)) * H_ + 8 * g;
        aq0 = *(const short8*)&qp[0];
        aq1 = *(const short8*)&qp[32];
    }

    short8 ones;                                 // bf16 1.0 fragment for l-MFMA
    #pragma unroll
    for (int j = 0; j < 8; ++j) ones[j] = (short)0x3F80;

    f32x4 o_acc[4];
    #pragma unroll
    for (int n = 0; n < 4; ++n) o_acc[n] = 0.0f;
    f32x4 l_acc = 0.0f;

    auto stage = [&](int buf, int gt) {
        const int key0 = gt * 64;
        #pragma unroll
        for (int j = 0; j < 2; ++j) {
            const int row = wid * 16 + j * 8;
            const unsigned short* gk = Kb
                + ((size_t)(batch * T_ + key0 + row + rsub)) * H_ + csw * 8;
            __builtin_amdgcn_global_load_lds(
                (const GLOBAL_AS unsigned int*)gk,
                (LDS_AS unsigned int*)&K_lds[buf][row][0], 16, 0, 0);
            const unsigned short* gv = Vt
                + ((size_t)(batch * H_ + row + rsub)) * T_ + key0 + csw * 8;
            __builtin_amdgcn_global_load_lds(
                (const GLOBAL_AS unsigned int*)gv,
                (LDS_AS unsigned int*)&V_lds[buf][row][0], 16, 0, 0);
        }
    };

    stage(0, ch * 8);
    __syncthreads();

    for (int t = 0; t < nt; ++t) {
        const int buf = t & 1;
        if (t + 1 < nt) stage(buf ^ 1, ch * 8 + t + 1);

        // ---- S = Q K^T (K frags from LDS, swizzled chunks) ----
        f32x4 sA[4];
        #pragma unroll
        for (int n = 0; n < 4; ++n) sA[n] = 0.0f;
        #pragma unroll
        for (int n = 0; n < 4; ++n) {
            short8 bk0 = *(const short8*)&K_lds[buf][n * 16 + c][cs0];
            short8 bk1 = *(const short8*)&K_lds[buf][n * 16 + c][cs1];
            sA[n] = __builtin_amdgcn_mfma_f32_16x16x32_bf16(aq0, bk0, sA[n], 0, 0, 0);
            sA[n] = __builtin_amdgcn_mfma_f32_16x16x32_bf16(aq1, bk1, sA[n], 0, 0, 0);
        }

        // ---- p = exp2(s); mask only the diagonal tile ----
        float pv[4][4];
        #pragma unroll
        for (int n = 0; n < 4; ++n)
            #pragma unroll
            for (int r = 0; r < 4; ++r)
                pv[n][r] = EXP2(sA[n][r]);
        if (t == lastt) {                        // wave-uniform branch
            const int d = (ch * 8 + t) * 64 + c - qbase - 4 * g;
            #pragma unroll
            for (int n = 0; n < 4; ++n)
                #pragma unroll
                for (int r = 0; r < 4; ++r)
                    if (d + 16 * n > r) pv[n][r] = 0.0f;
        }

        // ---- P: D-layout -> A-frag layout via per-wave LDS ----
        #pragma unroll
        for (int n = 0; n < 4; ++n)
            #pragma unroll
            for (int r = 0; r < 4; ++r)
                p_lds[wid][4 * g + r][n * 16 + c] = f2bf(pv[n][r]);
        short8 pa0 = *(const short8*)&p_lds[wid][c][8 * g];
        short8 pa1 = *(const short8*)&p_lds[wid][c][32 + 8 * g];

        // ---- l += P * 1 ----
        l_acc = __builtin_amdgcn_mfma_f32_16x16x32_bf16(pa0, ones, l_acc, 0, 0, 0);
        l_acc = __builtin_amdgcn_mfma_f32_16x16x32_bf16(pa1, ones, l_acc, 0, 0, 0);

        // ---- O += P V (V frags from LDS, swizzled chunks) ----
        #pragma unroll
        for (int n = 0; n < 4; ++n) {
            short8 bv0 = *(const short8*)&V_lds[buf][n * 16 + c][cs0];
            short8 bv1 = *(const short8*)&V_lds[buf][n * 16 + c][cs1];
            o_acc[n] = __builtin_amdgcn_mfma_f32_16x16x32_bf16(pa0, bv0, o_acc[n], 0, 0, 0);
            o_acc[n] = __builtin_amdgcn_mfma_f32_16x16x32_bf16(pa1, bv1, o_acc[n], 0, 0, 0);
        }

        __syncthreads();
    }

    unsigned short* po = Po + (size_t)slot * 1024;
    #pragma unroll
    for (int n = 0; n < 4; ++n)
        #pragma unroll
        for (int r = 0; r < 4; ++r)
            po[(4 * g + r) * 64 + n * 16 + c] = f2bf(o_acc[n][r]);
    if (c == 0) {
        #pragma unroll
        for (int r = 0; r < 4; ++r)
            Pl[slot * 16 + 4 * g + r] = l_acc[r];
    }
}

// ---------------------------------------------------------------------------
// Kernel 4: merge partials — plain sums. One wave per q-tile.
// ---------------------------------------------------------------------------
__global__ __launch_bounds__(256) void attn_merge_kernel(
    const unsigned short* __restrict__ Po, const float* __restrict__ Pl,
    float* __restrict__ out)
{
    const int tid  = threadIdx.x;
    const int wid  = tid >> 6, lane = tid & 63;
    const int gi   = blockIdx.x * 4 + wid;       // [0, 1024)
    const int batch = gi >> 8, qt = gi & 255;
    const int nkv  = (qt >> 2) + 1;
    const int npart = (nkv + 7) >> 3;
    const int Mm = nkv - 1, aa = Mm >> 3, rr8 = Mm & 7;
    const int slot0 = batch * 1152 + 4 * (4 * aa * (aa + 1) + rr8 * (aa + 1))
                    + (qt & 3) * npart;

    const int row = lane & 15, seg = lane >> 4;

    float lacc = 0.0f, o[16];
    #pragma unroll
    for (int k = 0; k < 16; ++k) o[k] = 0.0f;

    for (int i = 0; i < npart; ++i) {
        lacc += Pl[(slot0 + i) * 16 + row];
        const unsigned short* pp = Po + (size_t)(slot0 + i) * 1024 + row * 64 + seg * 16;
        short8 v0 = *(const short8*)&pp[0];
        short8 v1 = *(const short8*)&pp[8];
        #pragma unroll
        for (int k = 0; k < 8; ++k) {
            o[k]     += bf2f((unsigned short)v0[k]);
            o[8 + k] += bf2f((unsigned short)v1[k]);
        }
    }

    const float inv = 1.0f / lacc;
    float* op = out + ((size_t)(batch * T_ + qt * 16 + row)) * H_ + seg * 16;
    #pragma unroll
    for (int k = 0; k < 16; ++k) op[k] = o[k] * inv;
}

// ---------------------------------------------------------------------------
extern "C" void kernel_launch(void* const* d_in, const int* in_sizes, int n_in,
                              void* d_out, int out_size, void* d_ws, size_t ws_size,
                              hipStream_t stream)
{
    const float* x  = (const float*)d_in[0];
    const float* Wk = (const float*)d_in[1];
    const float* Wq = (const float*)d_in[2];
    const float* Wv = (const float*)d_in[3];
    float* out = (float*)d_out;

    // workspace layout:
    //   Wt  [3*64*1024] bf16            384 KB
    //   Qb/Kb [B*T*H] bf16            2+2 MB
    //   Vt  [B*H*T] bf16                  2 MB
    //   Po  [4608][16][64] bf16         9.4 MB
    //   Pl  [4608][16] f32              295 KB   total ~16.1 MB
    unsigned short* Wt = (unsigned short*)d_ws;
    unsigned short* Qb = Wt + 3 * 64 * 1024;
    unsigned short* Kb = Qb + (size_t)B_ * T_ * H_;
    unsigned short* Vt = Kb + (size_t)B_ * T_ * H_;
    unsigned short* Po = Vt + (size_t)B_ * T_ * H_;
    float* Pl = (float*)(Po + (size_t)4608 * 1024);

    hipLaunchKernelGGL(wt_transpose_kernel, dim3(48), dim3(256), 0, stream, Wq, Wk, Wv, Wt);
    hipLaunchKernelGGL(proj_kernel, dim3(256), dim3(768), 0, stream, x, Wt, Qb, Kb, Vt);
    hipLaunchKernelGGL(attn_split_kernel, dim3(2048), dim3(256), 0, stream, Qb, Kb, Vt, Po, Pl);
    hipLaunchKernelGGL(attn_merge_kernel, dim3(256), dim3(256), 0, stream, Po, Pl, out);
}